// Round 1
// baseline (66.140 us; speedup 1.0000x reference)
//
#include <hip/hip_runtime.h>
#include <math.h>

// out[b,i,h,w] = Ar[b,h,i]*cos(2*pi*i*w/128)/128 - Ai[b,h,i]*sin(2*pi*i*w/128)/128
// where A = row-DFT of input[:,0,:,:]  (fft2 then ifft over H == fft over W only).
// B=32, H=W=128. mask input is unused by the reference.

__global__ __launch_bounds__(128) void dft_rows(const float* __restrict__ x,
                                                float* __restrict__ Ar,
                                                float* __restrict__ Ai) {
    // blockIdx.x = b*128 + h ; threadIdx.x = frequency i
    const int bh = blockIdx.x;
    const int b  = bh >> 7;
    const int h  = bh & 127;
    const int i  = threadIdx.x;

    __shared__ __align__(16) float xrow[128];
    __shared__ __align__(16) float ct[128];
    __shared__ __align__(16) float st[128];

    xrow[i] = x[bh * 128 + i];
    float s, c;
    sincospif((float)i * (1.0f / 64.0f), &s, &c);   // angle 2*pi*i/128 = pi*(i/64)
    ct[i] = c;
    st[i] = s;
    __syncthreads();

    float ar = 0.0f, ai = 0.0f;
#pragma unroll
    for (int u = 0; u < 128; ++u) {
        const int k = (i * u) & 127;                 // exact mod-128 phase index
        ar = fmaf(xrow[u],  ct[k], ar);
        ai = fmaf(xrow[u], -st[k], ai);              // Im(fft) = -sum x*sin
    }
    const float inv = 1.0f / 128.0f;
    // store transposed A[b][i][h] with 1/W folded in
    const int o = (b * 128 + i) * 128 + h;
    Ar[o] = ar * inv;
    Ai[o] = ai * inv;
}

__global__ __launch_bounds__(256) void expand(const float* __restrict__ Ar,
                                              const float* __restrict__ Ai,
                                              float* __restrict__ out) {
    // blockIdx.x = b*128 + i ; writes one contiguous (h,w) plane of 128*128 f32
    const int bi = blockIdx.x;
    const int i  = bi & 127;
    const int t  = threadIdx.x;

    __shared__ __align__(16) float ah[128];   // Ar[b][i][h] / W
    __shared__ __align__(16) float ai_[128];  // Ai[b][i][h] / W
    __shared__ __align__(16) float cw[128];   // cos(2*pi*i*w/128)
    __shared__ __align__(16) float sw[128];   // sin(2*pi*i*w/128)

    if (t < 128) {
        float s, c;
        sincospif((float)((i * t) & 127) * (1.0f / 64.0f), &s, &c);
        cw[t] = c;
        sw[t] = s;
    } else {
        const int h = t - 128;
        ah[h]  = Ar[bi * 128 + h];
        ai_[h] = Ai[bi * 128 + h];
    }
    __syncthreads();

    float4* __restrict__ o4 = (float4*)(out + (size_t)bi * 16384);
    const float4* cw4 = (const float4*)cw;
    const float4* sw4 = (const float4*)sw;

#pragma unroll
    for (int j = 0; j < 16; ++j) {
        const int q  = t + j * 256;   // float4 index in plane, 0..4095, coalesced
        const int h  = q >> 5;        // 32 float4 per row of 128
        const int w4 = q & 31;
        const float a = ah[h];
        const float bb = ai_[h];
        const float4 cc = cw4[w4];
        const float4 ss = sw4[w4];
        float4 v;
        v.x = a * cc.x - bb * ss.x;
        v.y = a * cc.y - bb * ss.y;
        v.z = a * cc.z - bb * ss.z;
        v.w = a * cc.w - bb * ss.w;
        o4[q] = v;
    }
}

extern "C" void kernel_launch(void* const* d_in, const int* in_sizes, int n_in,
                              void* d_out, int out_size, void* d_ws, size_t ws_size,
                              hipStream_t stream) {
    const float* x = (const float*)d_in[0];   // (32,1,128,128) f32; mask (d_in[1]) unused
    float* out = (float*)d_out;               // (32,128,128,128) f32

    float* Ar = (float*)d_ws;                 // 32*128*128 f32 = 2 MB
    float* Ai = Ar + 32 * 128 * 128;          // 2 MB more

    dft_rows<<<dim3(4096), dim3(128), 0, stream>>>(x, Ar, Ai);
    expand<<<dim3(4096), dim3(256), 0, stream>>>(Ar, Ai, out);
}

// Round 2
// 50.148 us; speedup vs baseline: 1.3189x; 1.3189x over previous
//
#include <hip/hip_runtime.h>
#include <math.h>

// out[b,i,h,w] = Ar[b,h,i]*cos(2*pi*i*w/128)/128 - Ai[b,h,i]*sin(2*pi*i*w/128)/128
// where A = row-DFT of input[:,0,:,:]. B=32, H=W=128. mask input is unused.
//
// Fully fused: one block handles (b, group of 8 i's). x[b] staged in LDS once,
// per-i DFT computed cooperatively, output plane streamed with float4 stores.
// 512 blocks x 256 threads, 2 blocks/CU -> all blocks resident.

#define IPG 8  // i-values per block

__global__ __launch_bounds__(256, 2) void kspace_fused(const float* __restrict__ x,
                                                       float* __restrict__ out) {
    const int blk = blockIdx.x;      // 0..511
    const int b   = blk >> 4;        // batch
    const int ig  = blk & 15;        // i-group
    const int t   = threadIdx.x;

    __shared__ float xl[128 * 129];                    // x[b] padded (+1 f32 per row): 66 KB
    __shared__ __align__(16) float ct[128], st[128];   // exact phase tables cos/sin(2*pi*k/128)
    __shared__ __align__(16) float ar_[128], ai_[128]; // A[b][i][h]/W (sign folded)
    __shared__ __align__(16) float cw[128], sw[128];   // per-i trig rows for expand

    // exact trig table: angle 2*pi*k/128 = pi*(k/64)
    if (t < 128) {
        float s, c;
        sincospif((float)t * (1.0f / 64.0f), &s, &c);
        ct[t] = c;
        st[t] = s;
    }

    // stage x[b] (16384 floats) into padded LDS; scalar, coalesced
    const float* xb = x + (size_t)b * 16384;
#pragma unroll
    for (int r = 0; r < 64; ++r) {
        const int idx = t + r * 256;         // 0..16383
        const int h   = idx >> 7;
        const int u   = idx & 127;
        xl[h * 129 + u] = xb[idx];
    }
    __syncthreads();

    const int h    = t >> 1;                 // row owned by this thread-pair
    const int half = t & 1;                  // which 64-u half
    const float* xrow = &xl[h * 129 + half * 64];

    for (int ii = 0; ii < IPG; ++ii) {
        const int i = ig * IPG + ii;

        // ---- DFT: A[i][h] = sum_u x[h][u] * e^{-2*pi*i*u/128} ----
        float ar = 0.0f, aiv = 0.0f;
        const int ustart = half * 64;
#pragma unroll
        for (int j = 0; j < 64; ++j) {
            const int k = (i * (ustart + j)) & 127;   // exact mod-128 phase
            const float xv = xrow[j];
            ar  = fmaf(xv,  ct[k], ar);
            aiv = fmaf(xv, -st[k], aiv);              // Im(fft) = -sum x*sin
        }
        ar  += __shfl_xor(ar, 1);
        aiv += __shfl_xor(aiv, 1);
        if (half == 0) {
            ar_[h] = ar  * (1.0f / 128.0f);
            ai_[h] = aiv * (1.0f / 128.0f);
        }
        // per-i trig rows for the w-dimension (table lookup, exact)
        if (t < 128) {
            const int k2 = (i * t) & 127;
            cw[t] = ct[k2];
            sw[t] = st[k2];
        }
        __syncthreads();

        // ---- expand: write one contiguous 64 KB plane (b,i,:,:) ----
        float4* __restrict__ o4 = (float4*)(out + ((size_t)(b * 128 + i)) * 16384);
        const float4* cw4 = (const float4*)cw;
        const float4* sw4 = (const float4*)sw;
#pragma unroll
        for (int j = 0; j < 16; ++j) {
            const int q  = t + j * 256;      // float4 index in plane, coalesced
            const int hh = q >> 5;
            const int w4 = q & 31;
            const float a  = ar_[hh];
            const float bb = ai_[hh];
            const float4 cc = cw4[w4];
            const float4 ss = sw4[w4];
            float4 v;
            v.x = a * cc.x - bb * ss.x;
            v.y = a * cc.y - bb * ss.y;
            v.z = a * cc.z - bb * ss.z;
            v.w = a * cc.w - bb * ss.w;
            o4[q] = v;
        }
        __syncthreads();   // protect ar_/cw before next i overwrites
    }
}

extern "C" void kernel_launch(void* const* d_in, const int* in_sizes, int n_in,
                              void* d_out, int out_size, void* d_ws, size_t ws_size,
                              hipStream_t stream) {
    const float* x = (const float*)d_in[0];   // (32,1,128,128) f32; mask unused
    float* out = (float*)d_out;               // (32,128,128,128) f32
    kspace_fused<<<dim3(512), dim3(256), 0, stream>>>(x, out);
}